// Round 1
// baseline (66.848 us; speedup 1.0000x reference)
//
#include <hip/hip_runtime.h>
#include <cmath>

// Problem constants: N=64 graphs, K=64 nodes, C_IN=128, C=128.
#define NN 64
#define KKN 64
#define CCH 128
#define MM (NN * KKN) /* 4096 rows */

__device__ __forceinline__ float fast_tanh(float x) {
    // tanh(x) = 1 - 2/(exp(2x)+1); exp(2x) = exp2(x * 2*log2(e))
    float e = exp2f(x * 2.8853900817779268f);
    return 1.0f - 2.0f * __builtin_amdgcn_rcpf(e + 1.0f);
}

// Generic 64x64-tile fp32 GEMM: out = epilogue(X[M,128] @ Wrow[c,:].T)
// MODE 0: h = x@W_lin[:, :128].T + (b_lin + t*W_lin[:,128])        -> O0
// MODE 1: 384-col fused: c<128: T=tanh(.+bu1); c<256: A=.; else Bb=.+bb1
// MODE 2: out = T@Wu2.T + bu2                                      -> O0 (d_out)
// MODE 3: d_out += (S@Wb2.T + 63*bb2) / 64
template <int MODE>
__global__ __launch_bounds__(256) void gemm64(
    const float* __restrict__ X, const float* __restrict__ Wa,
    const float* __restrict__ Wb, const float* __restrict__ b0,
    const float* __restrict__ b1, const float* __restrict__ tptr,
    float* __restrict__ O0, float* __restrict__ O1, float* __restrict__ O2) {
    // Transposed LDS tiles [k][row], stride 68 (pad 4): 16B-aligned b128 reads,
    // bank = (4d + r) % 32 -> conflict-light.
    __shared__ float xT[128][68];
    __shared__ float wT[128][68];
    const int tid = threadIdx.x;
    const int base_r = blockIdx.x * 64;
    const int base_c = blockIdx.y * 64;

    // Stage X tile (64 rows x 128 k), transposed.
#pragma unroll
    for (int p = 0; p < 8; ++p) {
        const int idx = p * 256 + tid;
        const int row = idx >> 5;
        const int d4 = (idx & 31) << 2;
        const float4 v =
            *reinterpret_cast<const float4*>(X + (base_r + row) * 128 + d4);
        xT[d4 + 0][row] = v.x;
        xT[d4 + 1][row] = v.y;
        xT[d4 + 2][row] = v.z;
        xT[d4 + 3][row] = v.w;
    }
    // Stage W tile (64 cols x 128 k), transposed.
#pragma unroll
    for (int p = 0; p < 8; ++p) {
        const int idx = p * 256 + tid;
        const int cloc = idx >> 5;
        const int d4 = (idx & 31) << 2;
        const int c = base_c + cloc;
        if constexpr (MODE == 0) {
            // W_lin rows have stride 129 (odd) -> scalar loads (16B-unaligned).
            const float* wrow = Wa + c * 129;
            wT[d4 + 0][cloc] = wrow[d4 + 0];
            wT[d4 + 1][cloc] = wrow[d4 + 1];
            wT[d4 + 2][cloc] = wrow[d4 + 2];
            wT[d4 + 3][cloc] = wrow[d4 + 3];
        } else {
            const float* wrow;
            if constexpr (MODE == 1) {
                if (c < 128)
                    wrow = Wa + c * 128;              // Wu1
                else if (c < 256)
                    wrow = Wb + (c - 128) * 256;      // Wb1 left half
                else
                    wrow = Wb + (c - 256) * 256 + 128; // Wb1 right half
            } else {
                wrow = Wa + c * 128;
            }
            const float4 v = *reinterpret_cast<const float4*>(wrow + d4);
            wT[d4 + 0][cloc] = v.x;
            wT[d4 + 1][cloc] = v.y;
            wT[d4 + 2][cloc] = v.z;
            wT[d4 + 3][cloc] = v.w;
        }
    }
    __syncthreads();

    const int rg = (tid & 15) << 2;  // 4 rows
    const int cg = (tid >> 4) << 2;  // 4 cols
    float acc[4][4] = {};
#pragma unroll 8
    for (int d = 0; d < 128; ++d) {
        const float4 a = *reinterpret_cast<const float4*>(&xT[d][rg]);
        const float4 w = *reinterpret_cast<const float4*>(&wT[d][cg]);
        const float av[4] = {a.x, a.y, a.z, a.w};
        const float wv[4] = {w.x, w.y, w.z, w.w};
#pragma unroll
        for (int ii = 0; ii < 4; ++ii)
#pragma unroll
            for (int jj = 0; jj < 4; ++jj)
                acc[ii][jj] = fmaf(av[ii], wv[jj], acc[ii][jj]);
    }

#pragma unroll
    for (int jj = 0; jj < 4; ++jj) {
        const int c = base_c + cg + jj;
        float badd = 0.0f;
        if constexpr (MODE == 0) badd = b0[c] + tptr[0] * Wa[c * 129 + 128];
#pragma unroll
        for (int ii = 0; ii < 4; ++ii) {
            const int r = base_r + rg + ii;
            const float v = acc[ii][jj];
            if constexpr (MODE == 0) {
                O0[r * 128 + c] = v + badd;
            } else if constexpr (MODE == 1) {
                if (c < 128)
                    O0[r * 128 + c] = fast_tanh(v + b0[c]);       // T
                else if (c < 256)
                    O1[r * 128 + (c - 128)] = v;                  // A
                else
                    O2[r * 128 + (c - 256)] = v + b1[c - 256];    // Bb (+bb1)
            } else if constexpr (MODE == 2) {
                O0[r * 128 + c] = v + b0[c];
            } else {
                O0[r * 128 + c] += (v + 63.0f * b0[c]) * 0.015625f;
            }
        }
    }
}

// K3: S[n,j,c] = sum_{i != j} tanh(A[n,j,c] + Bb[n,i,c])
// Block = (graph n, 16-channel chunk). Bb rows staged in LDS; the inner-loop
// LDS read is wave-uniform (broadcast, conflict-free).
__global__ __launch_bounds__(256) void binary_sum(
    const float* __restrict__ A, const float* __restrict__ Bb,
    float* __restrict__ S) {
    const int n = blockIdx.x;
    const int cbase = blockIdx.y * 16;
    const int tid = threadIdx.x;
    __shared__ float bs[64][16];
    {
        const int i = tid >> 2;
        const int c4 = (tid & 3) << 2;
        const float4 v = *reinterpret_cast<const float4*>(
            Bb + (n * 64 + i) * 128 + cbase + c4);
        *reinterpret_cast<float4*>(&bs[i][c4]) = v;
    }
    __syncthreads();
    const int j = tid & 63;
    const int cq = (tid >> 6) << 2;
    const float4 a = *reinterpret_cast<const float4*>(
        A + (n * 64 + j) * 128 + cbase + cq);
    float s0 = 0.f, s1 = 0.f, s2 = 0.f, s3 = 0.f;
#pragma unroll 4
    for (int i = 0; i < 64; ++i) {
        const float4 b = *reinterpret_cast<const float4*>(&bs[i][cq]);
        s0 += fast_tanh(a.x + b.x);
        s1 += fast_tanh(a.y + b.y);
        s2 += fast_tanh(a.z + b.z);
        s3 += fast_tanh(a.w + b.w);
    }
    {  // remove diagonal i == j
        const float4 b = *reinterpret_cast<const float4*>(&bs[j][cq]);
        s0 -= fast_tanh(a.x + b.x);
        s1 -= fast_tanh(a.y + b.y);
        s2 -= fast_tanh(a.z + b.z);
        s3 -= fast_tanh(a.w + b.w);
    }
    float4 out = {s0, s1, s2, s3};
    *reinterpret_cast<float4*>(S + (n * 64 + j) * 128 + cbase + cq) = out;
}

extern "C" void kernel_launch(void* const* d_in, const int* in_sizes, int n_in,
                              void* d_out, int out_size, void* d_ws,
                              size_t ws_size, hipStream_t stream) {
    const float* t = (const float*)d_in[0];
    const float* x = (const float*)d_in[1];
    const float* W_lin = (const float*)d_in[2];
    const float* b_lin = (const float*)d_in[3];
    const float* Wu1 = (const float*)d_in[4];
    const float* bu1 = (const float*)d_in[5];
    const float* Wu2 = (const float*)d_in[6];
    const float* bu2 = (const float*)d_in[7];
    const float* Wb1 = (const float*)d_in[8];
    const float* bb1 = (const float*)d_in[9];
    const float* Wb2 = (const float*)d_in[10];
    const float* bb2 = (const float*)d_in[11];
    float* out = (float*)d_out;

    float* ws = (float*)d_ws;
    float* h = ws;                    // [4096,128], reused as S later
    float* A = ws + 1 * MM * CCH;     // [4096,128]
    float* Bb = ws + 2 * MM * CCH;    // [4096,128] (includes +bb1)
    float* T = ws + 3 * MM * CCH;     // [4096,128]
    float* S = h;                     // h is dead after mode-1 GEMM

    // 1) h = concat-linear(x, t)
    gemm64<0><<<dim3(64, 2), 256, 0, stream>>>(x, W_lin, nullptr, b_lin,
                                               nullptr, t, h, nullptr, nullptr);
    // 2) T = tanh(h@Wu1.T+bu1); A = h@Wb1_L.T; Bb = h@Wb1_R.T + bb1
    gemm64<1><<<dim3(64, 6), 256, 0, stream>>>(h, Wu1, Wb1, bu1, bb1, nullptr,
                                               T, A, Bb);
    // 3) out = T@Wu2.T + bu2   (unary)
    gemm64<2><<<dim3(64, 2), 256, 0, stream>>>(T, Wu2, nullptr, bu2, nullptr,
                                               nullptr, out, nullptr, nullptr);
    // 4) S[n,j] = sum_{i!=j} tanh(A[n,j] + Bb[n,i])
    binary_sum<<<dim3(64, 8), 256, 0, stream>>>(A, Bb, S);
    // 5) out += (S@Wb2.T + 63*bb2)/64   (binary)
    gemm64<3><<<dim3(64, 2), 256, 0, stream>>>(S, Wb2, nullptr, bb2, nullptr,
                                               nullptr, out, nullptr, nullptr);
    (void)in_sizes; (void)n_in; (void)out_size; (void)ws_size;
}

// Round 2
// 46.241 us; speedup vs baseline: 1.4456x; 1.4456x over previous
//
#include <hip/hip_runtime.h>

// Problem: N=64 graphs, K=64 nodes, C_IN=128, C=128, fp32.
#define MM 4096          // N*K rows
#define LS 132           // LDS row stride (dwords): 132%32=4 -> BW-optimal b128 col reads
#define ROW_ELEMS 524288 // 4096*128

__device__ __forceinline__ float tanh_fast(float x) {
    // tanh(x) = 1 - 2/(exp(2x)+1)
    float e = __builtin_amdgcn_exp2f(x * 2.8853900817779268f);
    return 1.0f - 2.0f * __builtin_amdgcn_rcpf(e + 1.0f);
}
__device__ __forceinline__ float sigterm(float x) {
    // 1/(exp(2x)+1); tanh(x) = 1 - 2*sigterm(x)
    float e = __builtin_amdgcn_exp2f(x * 2.8853900817779268f);
    return __builtin_amdgcn_rcpf(e + 1.0f);
}

// Stage 64 rows x 128 cols of X into xs (row-major, stride LS). Coalesced
// float4 loads; LDS writes are bank-uniform (4 dwords/bank per instr).
__device__ __forceinline__ void stage64(const float* __restrict__ X, int r0,
                                        float* __restrict__ xs, int tid) {
    const float4* src = reinterpret_cast<const float4*>(X + (size_t)r0 * 128);
#pragma unroll
    for (int p = 0; p < 8; ++p) {
        const int q = p * 256 + tid;          // 2048 float4s
        const int r = q >> 5;
        const int k4 = (q & 31) << 2;
        const float4 v = src[q];
        *reinterpret_cast<float4*>(&xs[r * LS + k4]) = v;
    }
}

// Inner product pass: lane's row (from LDS) dotted with 8 wave-uniform weight
// rows (scalarized to s_load by uniformity). 1 ds_read_b128 : 32 FMA.
#define ACCUM8(WROW)                                                        \
    _Pragma("unroll 2") for (int kq = 0; kq < 32; ++kq) {                   \
        const float4 a =                                                    \
            *reinterpret_cast<const float4*>(&xs[lane * LS + kq * 4]);      \
        _Pragma("unroll") for (int c = 0; c < 8; ++c) {                     \
            const float* w = (WROW)[c] + kq * 4;                            \
            acc[c] = fmaf(a.x, w[0], acc[c]);                               \
            acc[c] = fmaf(a.y, w[1], acc[c]);                               \
            acc[c] = fmaf(a.z, w[2], acc[c]);                               \
            acc[c] = fmaf(a.w, w[3], acc[c]);                               \
        }                                                                   \
    }

// MODE 0: h = x@W_lin[:, :128].T + b_lin + t*W_lin[:,128]          -> O0
// MODE 1: 384 fused cols: T=tanh(h@Wu1.T+bu1) -> O0, A=h@Wb1L.T -> O1,
//         Bb=h@Wb1R.T+bb1 -> O2
// MODE 2: out = T@Wu2.T + S'@Wb2.T + bu2 + (63/64)*bb2             -> O0
// Wave = 64 rows x 8 cols; block = 4 waves (32 cols); grid = (M/64, N/32).
template <int MODE>
__global__ __launch_bounds__(256) void gemm_sw(
    const float* __restrict__ X0, const float* __restrict__ X1,
    const float* __restrict__ Wa, const float* __restrict__ Wb,
    const float* __restrict__ b0, const float* __restrict__ b1,
    const float* __restrict__ tp, float* __restrict__ O0,
    float* __restrict__ O1, float* __restrict__ O2) {
    __shared__ float xs[64 * LS];
    const int tid = threadIdx.x;
    const int lane = tid & 63;
    const int wv = __builtin_amdgcn_readfirstlane(tid >> 6);
    const int r0 = blockIdx.x * 64;
    const int cg = blockIdx.y * 32 + wv * 8;  // first of this wave's 8 cols
    const int row = r0 + lane;

    stage64(X0, r0, xs, tid);
    __syncthreads();

    float acc[8] = {0.f, 0.f, 0.f, 0.f, 0.f, 0.f, 0.f, 0.f};
    const float* wrow[8];
    if constexpr (MODE == 0) {
#pragma unroll
        for (int c = 0; c < 8; ++c) wrow[c] = Wa + (cg + c) * 129;
    } else if constexpr (MODE == 1) {
#pragma unroll
        for (int c = 0; c < 8; ++c) {
            const int g = cg + c;
            wrow[c] = (g < 128) ? (Wa + g * 128)
                                : (g < 256 ? (Wb + (g - 128) * 256)
                                           : (Wb + (g - 256) * 256 + 128));
        }
    } else {
#pragma unroll
        for (int c = 0; c < 8; ++c) wrow[c] = Wa + (cg + c) * 128;
    }
    ACCUM8(wrow)

    if constexpr (MODE == 2) {
        __syncthreads();  // all waves done reading pass-A tile
        stage64(X1, r0, xs, tid);
        __syncthreads();
        const float* wrow2[8];
#pragma unroll
        for (int c = 0; c < 8; ++c) wrow2[c] = Wb + (cg + c) * 128;
        ACCUM8(wrow2)
    }

    float o[8];
    float* dst;
    int ccol = cg;
    if constexpr (MODE == 0) {
        const float tv = tp[0];
#pragma unroll
        for (int c = 0; c < 8; ++c)
            o[c] = acc[c] + b0[cg + c] + tv * Wa[(cg + c) * 129 + 128];
        dst = O0;
    } else if constexpr (MODE == 1) {
        if (cg < 128) {  // T = tanh(. + bu1)
#pragma unroll
            for (int c = 0; c < 8; ++c) o[c] = tanh_fast(acc[c] + b0[cg + c]);
            dst = O0;
        } else if (cg < 256) {  // A (raw)
#pragma unroll
            for (int c = 0; c < 8; ++c) o[c] = acc[c];
            dst = O1;
            ccol = cg - 128;
        } else {  // Bb = . + bb1
#pragma unroll
            for (int c = 0; c < 8; ++c) o[c] = acc[c] + b1[cg + c - 256];
            dst = O2;
            ccol = cg - 256;
        }
    } else {
#pragma unroll
        for (int c = 0; c < 8; ++c)
            o[c] = acc[c] + b0[cg + c] + 0.984375f * b1[cg + c];
        dst = O0;
    }
    float4 v0 = {o[0], o[1], o[2], o[3]};
    float4 v1 = {o[4], o[5], o[6], o[7]};
    *reinterpret_cast<float4*>(&dst[(size_t)row * 128 + ccol]) = v0;
    *reinterpret_cast<float4*>(&dst[(size_t)row * 128 + ccol + 4]) = v1;
}

// S'[n,j,c] = (sum_{i!=j} tanh(A[n,j,c]+Bb[n,i,c])) / 64
//           = (63 - 2*(R - sig_jj)) / 64,  R = sum_i sigterm(...)
// Block = (graph n, 16-channel chunk); Bb staged in LDS, inner read is
// wave-uniform (broadcast).
__global__ __launch_bounds__(256) void binary_sum(const float* __restrict__ A,
                                                  const float* __restrict__ Bb,
                                                  float* __restrict__ S) {
    const int n = blockIdx.x;
    const int cb = blockIdx.y * 16;
    const int tid = threadIdx.x;
    __shared__ float bs[64 * 16];
    {
        const int i = tid >> 2;
        const int c4 = (tid & 3) << 2;
        *reinterpret_cast<float4*>(&bs[i * 16 + c4]) =
            *reinterpret_cast<const float4*>(
                &Bb[(size_t)(n * 64 + i) * 128 + cb + c4]);
    }
    __syncthreads();
    const int j = tid & 63;
    const int cq = (tid >> 6) << 2;
    const float4 a = *reinterpret_cast<const float4*>(
        &A[(size_t)(n * 64 + j) * 128 + cb + cq]);
    float r0 = 0.f, r1 = 0.f, r2 = 0.f, r3 = 0.f;
#pragma unroll 8
    for (int i = 0; i < 64; ++i) {
        const float4 b = *reinterpret_cast<const float4*>(&bs[i * 16 + cq]);
        r0 += sigterm(a.x + b.x);
        r1 += sigterm(a.y + b.y);
        r2 += sigterm(a.z + b.z);
        r3 += sigterm(a.w + b.w);
    }
    const float4 bj = *reinterpret_cast<const float4*>(&bs[j * 16 + cq]);
    float4 o;
    o.x = (63.0f - 2.0f * (r0 - sigterm(a.x + bj.x))) * 0.015625f;
    o.y = (63.0f - 2.0f * (r1 - sigterm(a.y + bj.y))) * 0.015625f;
    o.z = (63.0f - 2.0f * (r2 - sigterm(a.z + bj.z))) * 0.015625f;
    o.w = (63.0f - 2.0f * (r3 - sigterm(a.w + bj.w))) * 0.015625f;
    *reinterpret_cast<float4*>(&S[(size_t)(n * 64 + j) * 128 + cb + cq]) = o;
}

extern "C" void kernel_launch(void* const* d_in, const int* in_sizes, int n_in,
                              void* d_out, int out_size, void* d_ws,
                              size_t ws_size, hipStream_t stream) {
    const float* t = (const float*)d_in[0];
    const float* x = (const float*)d_in[1];
    const float* W_lin = (const float*)d_in[2];
    const float* b_lin = (const float*)d_in[3];
    const float* Wu1 = (const float*)d_in[4];
    const float* bu1 = (const float*)d_in[5];
    const float* Wu2 = (const float*)d_in[6];
    const float* bu2 = (const float*)d_in[7];
    const float* Wb1 = (const float*)d_in[8];
    const float* bb1 = (const float*)d_in[9];
    const float* Wb2 = (const float*)d_in[10];
    const float* bb2 = (const float*)d_in[11];
    float* out = (float*)d_out;

    float* ws = (float*)d_ws;
    float* h = ws;
    float* A = ws + 1 * ROW_ELEMS;
    float* Bb = ws + 2 * ROW_ELEMS;
    float* T = ws + 3 * ROW_ELEMS;
    float* S = ws + 4 * ROW_ELEMS;

    // K1: h = concat-linear(x, t)                     grid 256 blocks
    gemm_sw<0><<<dim3(64, 4), 256, 0, stream>>>(x, nullptr, W_lin, nullptr,
                                                b_lin, nullptr, t, h, nullptr,
                                                nullptr);
    // K2: T, A, Bb (384 fused cols)                   grid 768 blocks
    gemm_sw<1><<<dim3(64, 12), 256, 0, stream>>>(h, nullptr, Wu1, Wb1, bu1,
                                                 bb1, nullptr, T, A, Bb);
    // K3: S' = (sum_{i!=j} tanh(A_j + Bb_i)) / 64     grid 512 blocks
    binary_sum<<<dim3(64, 8), 256, 0, stream>>>(A, Bb, S);
    // K4: out = T@Wu2.T + S'@Wb2.T + bu2 + 63/64*bb2  grid 256 blocks
    gemm_sw<2><<<dim3(64, 4), 256, 0, stream>>>(T, S, Wu2, Wb2, bu2, bb2,
                                                nullptr, out, nullptr, nullptr);
    (void)in_sizes; (void)n_in; (void)out_size; (void)ws_size;
}